// Round 1
// baseline (3579.118 us; speedup 1.0000x reference)
//
#include <hip/hip_runtime.h>
#include <cstddef>

// ---------------------------------------------------------------------------
// SNN forward, restructured as feed-forward pipeline (layers decouple in time):
//   prep:    transpose weights to [j][o] layout (w4 zero-padded to 128 cols)
//   encode:  per (b,j) 32-step LIF encoder -> 32-bit spike mask
//   gemm:    H[t,b,o] = scale * sum_j bit(mask[b,j],t) * wT[j,o]   (fp32)
//   lif:     per (b,o) integrate 32 steps of H -> next-layer spike mask
//   out_li:  leaky-integrator readout -> d_out [2048,100]
// fp32 throughout: the v>0.33 Heaviside amplifies quantization into spike
// flips; bf16 is a later experiment once we know the fp32 absmax headroom.
// ---------------------------------------------------------------------------

#define THREADS 256
#define TB 64    // batch tile per block
#define TO 128   // output tile per block
#define JC 32    // K-chunk staged in LDS

#define W1T_W (2048 * 512)
#define W2T_W (512 * 512)
#define W3T_W (512 * 256)
#define W4T_W (256 * 128)
#define WT_TOTAL (W1T_W + W2T_W + W3T_W + W4T_W)

__global__ __launch_bounds__(THREADS) void prep_kernel(
    const float* __restrict__ w1, const float* __restrict__ w2,
    const float* __restrict__ w3, const float* __restrict__ w4,
    float* __restrict__ wt)
{
  int idx = blockIdx.x * THREADS + threadIdx.x;
  if (idx < W1T_W) {
    int j = idx >> 9, o = idx & 511;
    wt[idx] = w1[o * 2048 + j];
  } else if (idx < W1T_W + W2T_W) {
    int r = idx - W1T_W;
    int j = r >> 9, o = r & 511;
    wt[idx] = w2[o * 512 + j];
  } else if (idx < W1T_W + W2T_W + W3T_W) {
    int r = idx - (W1T_W + W2T_W);
    int j = r >> 8, o = r & 255;
    wt[idx] = w3[o * 512 + j];
  } else if (idx < WT_TOTAL) {
    int r = idx - (W1T_W + W2T_W + W3T_W);
    int j = r >> 7, o = r & 127;
    wt[idx] = (o < 100) ? w4[o * 256 + j] : 0.0f;  // zero-pad 100 -> 128
  }
}

// ConstantCurrentLIFEncoder: v += 0.1*(c - v); z = (v-0.33)>0; if z: v=0.
__global__ __launch_bounds__(THREADS) void encoder_kernel(
    const float* __restrict__ x, const float* __restrict__ fscale,
    unsigned* __restrict__ em, int b0)
{
  int idx = blockIdx.x * THREADS + threadIdx.x;
  int b = idx >> 11, j = idx & 2047;
  float c = 2.0f * fscale[0] * x[((size_t)(b0 + b) << 11) + j];
  float v = 0.0f;
  unsigned m = 0u;
#pragma unroll
  for (int t = 0; t < 32; ++t) {
    v = v + 0.1f * (c - v);
    unsigned z = ((v - 0.33f) > 0.0f) ? 1u : 0u;
    m |= z << t;
    if (z) v = 0.0f;
  }
  em[idx] = m;
}

// H[t,b,o] = scale * sum_j bit(masks[b,j], t) * wT[j,o]
// block: one t, 64 b x 128 o; thread: 4 b x 8 o accumulators.
__global__ __launch_bounds__(THREADS) void gemm_bits_kernel(
    const unsigned* __restrict__ masks, const float* __restrict__ wT,
    float* __restrict__ H, int J, int O, int Bc,
    const float* __restrict__ scale_ptr)
{
  __shared__ float sA[JC][TB];   // spike floats (pre-scaled)
  __shared__ float sW[JC][TO];
  const int t = blockIdx.z;
  const int btile = blockIdx.y * TB;
  const int o0 = blockIdx.x * TO;
  const int tid = threadIdx.x;
  const float scale = scale_ptr ? 5.0f * scale_ptr[0] : 1.0f;
  const int og = tid & 15;   // o = o0 + og*8 + [0..8)
  const int bg = tid >> 4;   // b = btile + bg*4 + [0..4)

  float acc[4][8];
#pragma unroll
  for (int bb = 0; bb < 4; ++bb)
#pragma unroll
    for (int oo = 0; oo < 8; ++oo) acc[bb][oo] = 0.0f;

  for (int j0 = 0; j0 < J; j0 += JC) {
    __syncthreads();
    // stage spike bits -> scaled floats: JC*TB = 2048 words, 8/thread
#pragma unroll
    for (int l = 0; l < (JC * TB) / THREADS; ++l) {
      int idx = tid + l * THREADS;
      int jj = idx & (JC - 1);
      int bb = idx >> 5;
      unsigned w = masks[(size_t)(btile + bb) * J + (j0 + jj)];
      sA[jj][bb] = ((w >> t) & 1u) ? scale : 0.0f;
    }
    // stage weights: JC*TO = 4096 floats, 16/thread
#pragma unroll
    for (int l = 0; l < (JC * TO) / THREADS; ++l) {
      int idx = tid + l * THREADS;
      int oo = idx & (TO - 1);
      int jj = idx >> 7;
      sW[jj][oo] = wT[(size_t)(j0 + jj) * O + (o0 + oo)];
    }
    __syncthreads();
#pragma unroll
    for (int j = 0; j < JC; ++j) {
      const float4 a  = *(const float4*)&sA[j][bg * 4];
      const float4 wA = *(const float4*)&sW[j][og * 8];
      const float4 wB = *(const float4*)&sW[j][og * 8 + 4];
      const float av[4] = {a.x, a.y, a.z, a.w};
      const float wv[8] = {wA.x, wA.y, wA.z, wA.w, wB.x, wB.y, wB.z, wB.w};
#pragma unroll
      for (int bb = 0; bb < 4; ++bb)
#pragma unroll
        for (int oo = 0; oo < 8; ++oo)
          acc[bb][oo] = fmaf(av[bb], wv[oo], acc[bb][oo]);
    }
  }

#pragma unroll
  for (int bb = 0; bb < 4; ++bb) {
    int b = btile + bg * 4 + bb;
    size_t off = ((size_t)t * Bc + b) * O + o0 + og * 8;
    *(float4*)&H[off]     = make_float4(acc[bb][0], acc[bb][1], acc[bb][2], acc[bb][3]);
    *(float4*)&H[off + 4] = make_float4(acc[bb][4], acc[bb][5], acc[bb][6], acc[bb][7]);
  }
}

// lif_feed_forward_step over 32 steps: v uses OLD i, then i = 0.8*i + inp_t.
__global__ __launch_bounds__(THREADS) void lif_int_kernel(
    const float* __restrict__ H, unsigned* __restrict__ mout,
    int lgO, int Bc)
{
  int idx = blockIdx.x * THREADS + threadIdx.x;
  int O = 1 << lgO;
  int b = idx >> lgO, o = idx & (O - 1);
  const float* p = H + (size_t)b * O + o;
  size_t stride = (size_t)Bc << lgO;
  float v = 0.0f, cur = 0.0f;
  unsigned m = 0u;
#pragma unroll
  for (int t = 0; t < 32; ++t) {
    v = v + 0.1f * (cur - v);                      // v_dec (old i)
    unsigned z = ((v - 0.33f) > 0.0f) ? 1u : 0u;   // superspike fwd
    m |= z << t;
    if (z) v = 0.0f;                               // v_dec*(1-z)
    cur = 0.8f * cur + p[t * stride];              // i_dec + inp
  }
  mout[idx] = m;
}

// LILinearCell readout: vo uses OLD io; io = 0.8*io + H4_t. Output vo.
__global__ __launch_bounds__(THREADS) void out_li_kernel(
    const float* __restrict__ H4, float* __restrict__ out, int Bc, int b0)
{
  int idx = blockIdx.x * THREADS + threadIdx.x;
  int b = idx >> 7, c = idx & 127;
  const float* p = H4 + ((size_t)b << 7) + c;
  size_t stride = (size_t)Bc << 7;
  float v = 0.0f, cur = 0.0f;
#pragma unroll
  for (int t = 0; t < 32; ++t) {
    v = v + 0.1f * (cur - v);
    cur = 0.8f * cur + p[t * stride];
  }
  if (c < 100) out[(size_t)(b0 + b) * 100 + c] = v;
}

extern "C" void kernel_launch(void* const* d_in, const int* in_sizes, int n_in,
                              void* d_out, int out_size, void* d_ws, size_t ws_size,
                              hipStream_t stream)
{
  const float* x  = (const float*)d_in[0];
  const float* w1 = (const float*)d_in[1];
  const float* w2 = (const float*)d_in[2];
  const float* w3 = (const float*)d_in[3];
  const float* w4 = (const float*)d_in[4];
  const float* fs = (const float*)d_in[5];
  const float* es = (const float*)d_in[6];
  float* out = (float*)d_out;
  (void)in_sizes; (void)n_in; (void)out_size;

  // Adaptive batch chunk so we fit whatever ws_size we were given.
  // words = weights-T + enc mask + s1/s2/s3 masks + H buffer (32*Bc*512, reused
  // for G/H2/H3/H4 since each is dead before the next is written).
  int Bc = 2048;
  auto need = [](int bc) -> size_t {
    return ((size_t)WT_TOTAL + (size_t)bc * (2048 + 512 + 512 + 256) +
            (size_t)bc * 32 * 512) * 4;
  };
  while (Bc > 64 && need(Bc) > ws_size) Bc >>= 1;

  float* wt  = (float*)d_ws;
  float* w1t = wt;
  float* w2t = w1t + W1T_W;
  float* w3t = w2t + W2T_W;
  float* w4t = w3t + W3T_W;
  unsigned* em  = (unsigned*)(wt + WT_TOTAL);
  unsigned* s1m = em  + (size_t)Bc * 2048;
  unsigned* s2m = s1m + (size_t)Bc * 512;
  unsigned* s3m = s2m + (size_t)Bc * 512;
  float* G = (float*)(s3m + (size_t)Bc * 256);

  prep_kernel<<<WT_TOTAL / THREADS, THREADS, 0, stream>>>(w1, w2, w3, w4, wt);

  for (int b0 = 0; b0 < 2048; b0 += Bc) {
    encoder_kernel<<<(Bc * 2048) / THREADS, THREADS, 0, stream>>>(x, fs, em, b0);
    // layer 1: J=2048 -> O=512, scale = 5*encoder_scalar
    gemm_bits_kernel<<<dim3(512 / TO, Bc / TB, 32), THREADS, 0, stream>>>(
        em, w1t, G, 2048, 512, Bc, es);
    lif_int_kernel<<<(Bc * 512) / THREADS, THREADS, 0, stream>>>(G, s1m, 9, Bc);
    // layer 2: J=512 -> O=512
    gemm_bits_kernel<<<dim3(512 / TO, Bc / TB, 32), THREADS, 0, stream>>>(
        s1m, w2t, G, 512, 512, Bc, nullptr);
    lif_int_kernel<<<(Bc * 512) / THREADS, THREADS, 0, stream>>>(G, s2m, 9, Bc);
    // layer 3: J=512 -> O=256
    gemm_bits_kernel<<<dim3(256 / TO, Bc / TB, 32), THREADS, 0, stream>>>(
        s2m, w3t, G, 512, 256, Bc, nullptr);
    lif_int_kernel<<<(Bc * 256) / THREADS, THREADS, 0, stream>>>(G, s3m, 8, Bc);
    // readout matmul: J=256 -> O=128 (padded)
    gemm_bits_kernel<<<dim3(128 / TO, Bc / TB, 32), THREADS, 0, stream>>>(
        s3m, w4t, G, 256, 128, Bc, nullptr);
    out_li_kernel<<<(Bc * 128) / THREADS, THREADS, 0, stream>>>(G, out, Bc, b0);
  }
}

// Round 3
// 2243.684 us; speedup vs baseline: 1.5952x; 1.5952x over previous
//
#include <hip/hip_runtime.h>
#include <cstddef>

// ---------------------------------------------------------------------------
// SNN forward, feed-forward pipeline. CORRECTNESS CONTRACT (R2 post-mortem):
// the spike threshold (v>0.33) amplifies any accumulation-order change into
// discrete spike flips vs the numpy reference. R1 (sequential-in-j fp32 fmaf,
// av in {0,scale}) passed at absmax 1.5e-5; R2's exact-integer MFMA failed at
// 2.4e-2 despite being MORE accurate. Therefore this kernel reproduces R1's
// arithmetic BIT-IDENTICALLY (same fmaf chain per (t,b,o): j strictly
// ascending, av in {0,scale}, w[o][j] operand) and only restructures for
// throughput:
//   - all 32 t folded into each block (masks read once, not 32x)
//   - bit-transposed masks so the (b,t)-chunk word sits in a register
//   - spike gating via sign-splat AND (2-3 VALU per (b,j), amortized over 32 o)
//   - W chunk staged [j][o] in LDS, +4 pad, float4 reads (<=2-way conflicts)
// ---------------------------------------------------------------------------

#define THREADS 256

// pad w_out [100][256] -> [128][256] (values identical where o<100)
__global__ __launch_bounds__(THREADS) void pad_w4_kernel(
    const float* __restrict__ w4, float* __restrict__ w4p)
{
  int idx = blockIdx.x * THREADS + threadIdx.x;   // 32768 total
  int o = idx >> 8, j = idx & 255;
  w4p[idx] = (o < 100) ? w4[o * 256 + j] : 0.0f;
}

// ConstantCurrentLIFEncoder (verbatim R1): v += 0.1*(c-v); z=(v-0.33)>0; reset.
__global__ __launch_bounds__(THREADS) void encoder_kernel(
    const float* __restrict__ x, const float* __restrict__ fscale,
    unsigned* __restrict__ em, int b0)
{
  int idx = blockIdx.x * THREADS + threadIdx.x;
  int b = idx >> 11, j = idx & 2047;
  float c = 2.0f * fscale[0] * x[((size_t)(b0 + b) << 11) + j];
  float v = 0.0f;
  unsigned m = 0u;
#pragma unroll
  for (int t = 0; t < 32; ++t) {
    v = v + 0.1f * (c - v);
    unsigned z = ((v - 0.33f) > 0.0f) ? 1u : 0u;
    m |= z << t;
    if (z) v = 0.0f;
  }
  em[idx] = m;
}

// Bit-transpose masks: em [Bc][J] word(b,j)=bits over t
//                  ->  emT [Bc][J/32][32] word(b,c,t)=bits over jj
// Pure bit moves — no arithmetic surface.
__global__ __launch_bounds__(THREADS) void tmask_kernel(
    const unsigned* __restrict__ em, unsigned* __restrict__ emT, int lgnc)
{
  __shared__ unsigned sm[8][33];
  int tile = threadIdx.x >> 5, l = threadIdx.x & 31;
  size_t gt = (size_t)blockIdx.x * 8 + tile;        // gt = b*nc + c
  int c = (int)(gt & ((1u << lgnc) - 1));
  size_t b = gt >> lgnc;
  sm[tile][l] = em[(b << (lgnc + 5)) + c * 32 + l]; // jj = l
  __syncthreads();
  unsigned w = 0;
#pragma unroll
  for (int jj = 0; jj < 32; ++jj) w |= ((sm[tile][jj] >> l) & 1u) << jj;
  emT[(gt << 5) + l] = w;                           // t = l
}

// ---------------------------------------------------------------------------
// Sequential-fp32 GEMM, bit-identical to R1's accumulation:
//   H[t,b,o] = chain_{j=0..J-1} fmaf(bit(b,t,j) ? scale : 0, W[o][j], acc)
// Block: OTILE o's x BB b's x all 32 t. Thread: t = tid&31, og = tid>>5,
// owns acc[BB][OTILE/8]. Masks pre-transposed so word (b, chunk, t) gives
// bits over j. W chunk staged in LDS [32][OTILE+4].
// ---------------------------------------------------------------------------
template <int OTILE, int BB>
__global__ __launch_bounds__(THREADS, 2) void gemm_seq_kernel(
    const unsigned* __restrict__ mT, const float* __restrict__ W,
    float* __restrict__ H, int J, int O, int Bc,
    const float* __restrict__ es)
{
  constexpr int OVEC = OTILE / 8;
  __shared__ float sW[32][OTILE + 4];
  const int tid = threadIdx.x;
  const int t = tid & 31, og = tid >> 5;
  const int o0 = blockIdx.x * OTILE;
  const int btile = blockIdx.y * BB;
  const int nc = J >> 5;
  const float scale = es ? 5.0f * es[0] : 1.0f;   // same expr as R1
  const int scale_i = __float_as_int(scale);

  float acc[BB][OVEC];
#pragma unroll
  for (int bb = 0; bb < BB; ++bb)
#pragma unroll
    for (int oo = 0; oo < OVEC; ++oo) acc[bb][oo] = 0.0f;

  for (int c = 0; c < nc; ++c) {
    // chunk masks: word (b, c, t) -> bits jj (issued early, consumed post-barrier)
    unsigned m[BB];
#pragma unroll
    for (int bb = 0; bb < BB; ++bb)
      m[bb] = mT[(((size_t)(btile + bb) * nc + c) << 5) + t];

    __syncthreads();
    if constexpr (OTILE == 256) {
      // thread -> one o-row, 32 j
      const float4* src = (const float4*)(W + (size_t)(o0 + tid) * J + c * 32);
      float4 f[8];
#pragma unroll
      for (int i = 0; i < 8; ++i) f[i] = src[i];
#pragma unroll
      for (int i = 0; i < 8; ++i) {
        sW[i * 4 + 0][tid] = f[i].x; sW[i * 4 + 1][tid] = f[i].y;
        sW[i * 4 + 2][tid] = f[i].z; sW[i * 4 + 3][tid] = f[i].w;
      }
    } else {  // OTILE == 128: 2 threads per o-row, 16 j each
      int oo = tid >> 1, jh = (tid & 1) << 4;
      const float4* src =
          (const float4*)(W + (size_t)(o0 + oo) * J + c * 32 + jh);
      float4 f[4];
#pragma unroll
      for (int i = 0; i < 4; ++i) f[i] = src[i];
#pragma unroll
      for (int i = 0; i < 4; ++i) {
        sW[jh + i * 4 + 0][oo] = f[i].x; sW[jh + i * 4 + 1][oo] = f[i].y;
        sW[jh + i * 4 + 2][oo] = f[i].z; sW[jh + i * 4 + 3][oo] = f[i].w;
      }
    }
    __syncthreads();

#pragma unroll 8
    for (int j = 0; j < 32; ++j) {
      float wv[OVEC];
#pragma unroll
      for (int q = 0; q < OVEC / 4; ++q)
        *(float4*)&wv[q * 4] = *(const float4*)&sW[j][og * OVEC + q * 4];
#pragma unroll
      for (int bb = 0; bb < BB; ++bb) {
        // av = bit ? scale : 0.0f  (sign-splat & trick, no branch)
        float av = __int_as_float((-(int)((m[bb] >> j) & 1u)) & scale_i);
#pragma unroll
        for (int oo = 0; oo < OVEC; ++oo)
          acc[bb][oo] = fmaf(av, wv[oo], acc[bb][oo]);
      }
    }
  }

#pragma unroll
  for (int bb = 0; bb < BB; ++bb) {
    size_t off = ((size_t)t * Bc + btile + bb) * O + o0 + og * OVEC;
#pragma unroll
    for (int q = 0; q < OVEC / 4; ++q)
      *(float4*)&H[off + q * 4] = make_float4(acc[bb][q * 4], acc[bb][q * 4 + 1],
                                              acc[bb][q * 4 + 2], acc[bb][q * 4 + 3]);
  }
}

// lif step over 32 t (verbatim R1): v uses OLD i; i = 0.8*i + inp_t.
__global__ __launch_bounds__(THREADS) void lif_int_kernel(
    const float* __restrict__ H, unsigned* __restrict__ mout,
    int lgO, int Bc)
{
  int idx = blockIdx.x * THREADS + threadIdx.x;
  int O = 1 << lgO;
  int b = idx >> lgO, o = idx & (O - 1);
  const float* p = H + (size_t)b * O + o;
  size_t stride = (size_t)Bc << lgO;
  float v = 0.0f, cur = 0.0f;
  unsigned m = 0u;
#pragma unroll
  for (int t = 0; t < 32; ++t) {
    v = v + 0.1f * (cur - v);
    unsigned z = ((v - 0.33f) > 0.0f) ? 1u : 0u;
    m |= z << t;
    if (z) v = 0.0f;
    cur = 0.8f * cur + p[t * stride];
  }
  mout[idx] = m;
}

// LILinearCell readout (verbatim R1).
__global__ __launch_bounds__(THREADS) void out_li_kernel(
    const float* __restrict__ H4, float* __restrict__ out, int Bc, int b0)
{
  int idx = blockIdx.x * THREADS + threadIdx.x;
  int b = idx >> 7, c = idx & 127;
  const float* p = H4 + ((size_t)b << 7) + c;
  size_t stride = (size_t)Bc << 7;
  float v = 0.0f, cur = 0.0f;
#pragma unroll
  for (int t = 0; t < 32; ++t) {
    v = v + 0.1f * (cur - v);
    cur = 0.8f * cur + p[t * stride];
  }
  if (c < 100) out[(size_t)(b0 + b) * 100 + c] = v;
}

extern "C" void kernel_launch(void* const* d_in, const int* in_sizes, int n_in,
                              void* d_out, int out_size, void* d_ws, size_t ws_size,
                              hipStream_t stream)
{
  const float* x  = (const float*)d_in[0];
  const float* w1 = (const float*)d_in[1];
  const float* w2 = (const float*)d_in[2];
  const float* w3 = (const float*)d_in[3];
  const float* w4 = (const float*)d_in[4];
  const float* fs = (const float*)d_in[5];
  const float* es = (const float*)d_in[6];
  float* out = (float*)d_out;
  (void)in_sizes; (void)n_in; (void)out_size;

  // workspace: w4 pad + (em,emT) + (s1m,s1mT) + (s2m,s2mT) + (s3m,s3mT) + H
  int Bc = 2048;
  auto need = [](int bc) -> size_t {
    return ((size_t)32768 +
            (size_t)bc * (2 * 2048 + 2 * 512 + 2 * 512 + 2 * 256) +
            (size_t)bc * 32 * 512) * 4;
  };
  while (Bc > 64 && need(Bc) > ws_size) Bc >>= 1;

  float* w4p = (float*)d_ws;
  unsigned* em   = (unsigned*)(w4p + 32768);
  unsigned* emT  = em   + (size_t)Bc * 2048;
  unsigned* s1m  = emT  + (size_t)Bc * 2048;
  unsigned* s1mT = s1m  + (size_t)Bc * 512;
  unsigned* s2m  = s1mT + (size_t)Bc * 512;
  unsigned* s2mT = s2m  + (size_t)Bc * 512;
  unsigned* s3m  = s2mT + (size_t)Bc * 512;
  unsigned* s3mT = s3m  + (size_t)Bc * 256;
  float* H = (float*)(s3mT + (size_t)Bc * 256);

  pad_w4_kernel<<<32768 / THREADS, THREADS, 0, stream>>>(w4, w4p);

  for (int b0 = 0; b0 < 2048; b0 += Bc) {
    encoder_kernel<<<(Bc * 2048) / THREADS, THREADS, 0, stream>>>(x, fs, em, b0);
    // layer 1: J=2048 -> O=512, scale = 5*encoder_scalar
    tmask_kernel<<<(Bc * 64) / 8, THREADS, 0, stream>>>(em, emT, 6);
    gemm_seq_kernel<256, 4><<<dim3(2, Bc / 4), THREADS, 0, stream>>>(
        emT, w1, H, 2048, 512, Bc, es);
    lif_int_kernel<<<(Bc * 512) / THREADS, THREADS, 0, stream>>>(H, s1m, 9, Bc);
    // layer 2: J=512 -> O=512
    tmask_kernel<<<(Bc * 16) / 8, THREADS, 0, stream>>>(s1m, s1mT, 4);
    gemm_seq_kernel<256, 4><<<dim3(2, Bc / 4), THREADS, 0, stream>>>(
        s1mT, w2, H, 512, 512, Bc, nullptr);
    lif_int_kernel<<<(Bc * 512) / THREADS, THREADS, 0, stream>>>(H, s2m, 9, Bc);
    // layer 3: J=512 -> O=256
    tmask_kernel<<<(Bc * 16) / 8, THREADS, 0, stream>>>(s2m, s2mT, 4);
    gemm_seq_kernel<256, 4><<<dim3(1, Bc / 4), THREADS, 0, stream>>>(
        s2mT, w3, H, 512, 256, Bc, nullptr);
    lif_int_kernel<<<(Bc * 256) / THREADS, THREADS, 0, stream>>>(H, s3m, 8, Bc);
    // readout matmul: J=256 -> O=128 (padded)
    tmask_kernel<<<(Bc * 8) / 8, THREADS, 0, stream>>>(s3m, s3mT, 3);
    gemm_seq_kernel<128, 8><<<dim3(1, Bc / 8), THREADS, 0, stream>>>(
        s3mT, w4p, H, 256, 128, Bc, nullptr);
    out_li_kernel<<<(Bc * 128) / THREADS, THREADS, 0, stream>>>(H, out, Bc, b0);
  }
}